// Round 6
// baseline (2872.769 us; speedup 1.0000x reference)
//
#include <hip/hip_runtime.h>
#include <hip/hip_fp16.h>

#define BB 128
#define NN 512
#define HH 128
#define TT 4

typedef _Float16 f16;
typedef _Float16 half8 __attribute__((ext_vector_type(8)));
typedef float floatx4 __attribute__((ext_vector_type(4)));

// fp32 -> f16 hi/lo split: x ~= hi + lo, |lo| <= |x|*2^-11
__device__ __forceinline__ void split1(float x, f16& hi, f16& lo) {
  hi = (f16)x;
  lo = (f16)(x - (float)hi);
}

// async global->LDS 16B (wave-uniform LDS base + lane*16; global src per-lane)
#define GLL16(gp, lp) __builtin_amdgcn_global_load_lds( \
    (const __attribute__((address_space(1))) void*)(const void*)(gp), \
    (__attribute__((address_space(3))) void*)(void*)(lp), 16, 0, 0)

// ---------- one-time prep ----------

// six HxH fp32 weights, pre-scaled x16, split into f16 hi/lo
__global__ void k_wsplit(const float* __restrict__ wz, const float* __restrict__ uz,
                         const float* __restrict__ wr, const float* __restrict__ ur,
                         const float* __restrict__ wc, const float* __restrict__ uc,
                         f16* __restrict__ whi, f16* __restrict__ wlo) {
  int mat = blockIdx.x >> 6;
  int idx = ((blockIdx.x & 63) << 8) + threadIdx.x;
  const float* src = mat==0?wz : mat==1?uz : mat==2?wr : mat==3?ur : mat==4?wc : uc;
  float v = src[idx] * 16.0f;
  f16 hi, lo; split1(v, hi, lo);
  whi[mat*16384 + idx] = hi;
  wlo[mat*16384 + idx] = lo;
}

// summed gate biases: [0]=b_wz+b_uz, [1]=b_wr+b_ur, [2]=b_w+b_u
__global__ void k_bsum(const float* __restrict__ bwz, const float* __restrict__ buz,
                       const float* __restrict__ bwr, const float* __restrict__ bur,
                       const float* __restrict__ bw,  const float* __restrict__ bu,
                       float* __restrict__ bias3) {
  int b = blockIdx.x, j = threadIdx.x;
  bias3[b*HH + j] = b==0 ? bwz[j]+buz[j] : (b==1 ? bwr[j]+bur[j] : bw[j]+bu[j]);
}

__global__ void k_copy_h0(const float* __restrict__ hin, float* __restrict__ h) {
  int v = blockIdx.x * 256 + threadIdx.x;
  ((float4*)h)[v] = ((const float4*)hin)[v];
}

// ---------- per-step kernels ----------

// a32[b][n][j] = b_ah[j] + sum_m A[b][m][n] * h[b][m][j], fp32-accurate via
// hi/lo split f16 MFMA (3 passes). In-kernel transpose staging, XOR-swizzled.
// grid (4 n-tiles, 128 batch), 256 thr (4 waves), tile 128x128, BK=64.
__global__ __launch_bounds__(256) void k_biggemm(const float* __restrict__ A,
                                                 const float* __restrict__ h,
                                                 const float* __restrict__ b_ah,
                                                 float* __restrict__ a32) {
  __shared__ __align__(16) f16 Ah[128*64], Al[128*64], Hh[128*64], Hl[128*64];
  const int b = blockIdx.y, n0 = blockIdx.x * 128, tid = threadIdx.x;
  const int w = tid >> 6, L = tid & 63, quad = L >> 4, l16 = L & 15;
  const int rowsel = tid >> 5, colsel = tid & 31;
  const float* Ab = A + (size_t)b * NN * NN;
  const float* hb = h + (size_t)b * NN * HH;
  const floatx4 zero = {0.f, 0.f, 0.f, 0.f};
  floatx4 acc[2][8];
  for (int sr = 0; sr < 2; sr++) for (int sc = 0; sc < 8; sc++) acc[sr][sc] = zero;

  for (int mc = 0; mc < NN; mc += 64) {
    float4 va[8], vh[8];
#pragma unroll
    for (int i = 0; i < 8; i++) {
      int mm = rowsel * 8 + i;
      va[i] = *(const float4*)(Ab + (size_t)(mc + mm) * NN + n0 + colsel * 4);
      vh[i] = *(const float4*)(hb + (size_t)(mc + mm) * HH + colsel * 4);
    }
#pragma unroll
    for (int q = 0; q < 4; q++) {
      int c = colsel * 4 + q;
      half8 avh, avl, hvh, hvl;
#pragma unroll
      for (int i = 0; i < 8; i++) {
        f16 hi, lo;
        split1(((const float*)&va[i])[q], hi, lo); avh[i] = hi; avl[i] = lo;
        split1(((const float*)&vh[i])[q], hi, lo); hvh[i] = hi; hvl[i] = lo;
      }
      int blk = (rowsel ^ (c & 7)) * 8;
      *(half8*)&Ah[c*64 + blk] = avh;  *(half8*)&Al[c*64 + blk] = avl;
      *(half8*)&Hh[c*64 + blk] = hvh;  *(half8*)&Hl[c*64 + blk] = hvl;
    }
    __syncthreads();
#pragma unroll
    for (int ks = 0; ks < 2; ks++) {
      const int kb = ks * 4 + quad;
      half8 afh[2], afl[2], bfh[8], bfl[8];
      for (int sr = 0; sr < 2; sr++) {
        int c = w*32 + sr*16 + l16, o = c*64 + ((kb ^ (c & 7)) * 8);
        afh[sr] = *(const half8*)&Ah[o];
        afl[sr] = *(const half8*)&Al[o];
      }
      for (int sc = 0; sc < 8; sc++) {
        int c = sc*16 + l16, o = c*64 + ((kb ^ (c & 7)) * 8);
        bfh[sc] = *(const half8*)&Hh[o];
        bfl[sc] = *(const half8*)&Hl[o];
      }
      for (int sr = 0; sr < 2; sr++)
        for (int sc = 0; sc < 8; sc++) {
          acc[sr][sc] = __builtin_amdgcn_mfma_f32_16x16x32_f16(afh[sr], bfh[sc], acc[sr][sc], 0, 0, 0);
          acc[sr][sc] = __builtin_amdgcn_mfma_f32_16x16x32_f16(afh[sr], bfl[sc], acc[sr][sc], 0, 0, 0);
          acc[sr][sc] = __builtin_amdgcn_mfma_f32_16x16x32_f16(afl[sr], bfh[sc], acc[sr][sc], 0, 0, 0);
        }
    }
    __syncthreads();
  }
  float bah[8];
  for (int sc = 0; sc < 8; sc++) bah[sc] = b_ah[sc*16 + l16];
  float* ab = a32 + (size_t)b * NN * HH;
#pragma unroll
  for (int sr = 0; sr < 2; sr++)
    for (int rg = 0; rg < 4; rg++) {
      const int row = n0 + w*32 + sr*16 + quad*4 + rg;   // C/D: row=quad*4+reg
      for (int sc = 0; sc < 8; sc++)
        ab[(size_t)row*HH + sc*16 + l16] = acc[sr][sc][rg] + bah[sc];  // col=lane&15
    }
}

// gates, 128 rows of [B*N] per block (512 blocks), 256 thr = 4 waves, each wave
// owns 32 rows. Numerics IDENTICAL to round-4 (all six hi/lo MFMA terms per
// gate incl. rh-lo; zacc fp32 to the end) -- round-5's precision cuts failed.
// Weights staged via global_load_lds 16B bulk-async, 2 mats (32-K slice) per
// round -> wbuf 16 KB; per ks: round A {W_h,U_h} feeds 64 MFMAs/wave, round B
// {W_l,U_l} feeds 32. Global source pre-swizzled (chunk^=(row>>1)&3) so linear
// LDS fill + swizzled ds_read_b128 is 2-way = free.
// rh hi/lo in UNPADDED XOR-swizzled LDS (chunk^=(row&7)): 64 KB exactly.
// Total LDS 80 KB -> 2 blocks/CU, same as round 4.
__global__ __launch_bounds__(256, 2) void k_gates(const float* __restrict__ a32,
                                                  float* __restrict__ h,
                                                  const f16* __restrict__ whi,
                                                  const f16* __restrict__ wlo,
                                                  const float* __restrict__ bias3) {
  __shared__ __align__(16) f16 wbuf[8192];            // 16 KB: 2 mats x [128][32]
  __shared__ __align__(16) f16 rhh[16384], rhl[16384]; // 64 KB: rh hi/lo, swizzled
  const int row0 = blockIdx.x << 7, tid = threadIdx.x;
  const int w = tid >> 6, L = tid & 63, quad = L >> 4, l16 = L & 15;

  // ---- persistent a/h fragments (A-op layout m=lane&15, k=quad*8+j) ----
  const float* ap[2]; const float* hp[2];
  for (int sr = 0; sr < 2; sr++) {
    int r = row0 + w*32 + sr*16 + l16;
    ap[sr] = a32 + (size_t)r * HH;
    hp[sr] = h + (size_t)r * HH;
  }
  half8 afh[2][4], afl[2][4], hfh[2][4], hfl[2][4];
#pragma unroll
  for (int sr = 0; sr < 2; sr++)
#pragma unroll
    for (int ks = 0; ks < 4; ks++) {
      const int ko = ks*32 + quad*8;
      float4 p = *(const float4*)(ap[sr] + ko);
      float4 q2 = *(const float4*)(ap[sr] + ko + 4);
      const float* v = (const float*)&p;
      const float* v2 = (const float*)&q2;
      for (int i = 0; i < 4; i++) { f16 hi, lo; split1(v[i],  hi, lo); afh[sr][ks][i]   = hi; afl[sr][ks][i]   = lo; }
      for (int i = 0; i < 4; i++) { f16 hi, lo; split1(v2[i], hi, lo); afh[sr][ks][i+4] = hi; afl[sr][ks][i+4] = lo; }
      float4 hpv = *(const float4*)(hp[sr] + ko);
      float4 hqv = *(const float4*)(hp[sr] + ko + 4);
      const float* hv1 = (const float*)&hpv;
      const float* hv2 = (const float*)&hqv;
      for (int i = 0; i < 4; i++) { f16 hi, lo; split1(hv1[i], hi, lo); hfh[sr][ks][i]   = hi; hfl[sr][ks][i]   = lo; }
      for (int i = 0; i < 4; i++) { f16 hi, lo; split1(hv2[i], hi, lo); hfh[sr][ks][i+4] = hi; hfl[sr][ks][i+4] = lo; }
    }
  const floatx4 zero = {0.f, 0.f, 0.f, 0.f};

  // staging: lane covers one 16B chunk; global chunk pre-swizzled so the
  // LINEAR LDS fill realizes LDS[r][c] = global[r][c ^ ((r>>1)&3)].
  const int rq = L >> 2;                         // row within 16-row wave span
  const int qf = (L & 3) ^ ((L >> 3) & 3);
  auto STAGE2 = [&](const f16* m0, const f16* m1, int ks) {
#pragma unroll
    for (int hf2 = 0; hf2 < 2; hf2++) {
      const int r = hf2*64 + w*16 + rq;
      const int go = r*HH + ks*32 + qf*8;
      f16* lp = (f16*)wbuf + hf2*2048 + w*512;   // wave-uniform; +lane*8 implicit
      GLL16(m0 + go, lp);
      GLL16(m1 + go, lp + 4096);
    }
  };
  // swizzled ds_read of a B-fragment: row=sc*16+l16, k-chunk=quad
  auto LDW = [&](int mat, int sc) -> half8 {
    const int e = mat*4096 + (sc*16 + l16)*32 + ((quad ^ ((l16>>1)&3)))*8;
    return *(const half8*)&wbuf[e];
  };
  // rh swizzle: element offset for (row, col-chunk q, j) = row*128 + (q^(row&7))*8 + j

  const f16* Wz_h = whi;            const f16* Wz_l = wlo;
  const f16* Uz_h = whi + 16384;    const f16* Uz_l = wlo + 16384;
  const f16* Wr_h = whi + 2*16384;  const f16* Wr_l = wlo + 2*16384;
  const f16* Ur_h = whi + 3*16384;  const f16* Ur_l = wlo + 3*16384;
  const f16* Wc_h = whi + 4*16384;  const f16* Wc_l = wlo + 4*16384;
  const f16* Uc_h = whi + 5*16384;  const f16* Uc_l = wlo + 5*16384;

  // ---- Pass 1: r = sigmoid(a Wr^T + h Ur^T + b) ----
  floatx4 racc[2][8];
  for (int sr = 0; sr < 2; sr++) for (int sc = 0; sc < 8; sc++) racc[sr][sc] = zero;
#pragma unroll 1
  for (int ks = 0; ks < 4; ks++) {
    STAGE2(Wr_h, Ur_h, ks);
    asm volatile("s_waitcnt vmcnt(0)" ::: "memory");
    __syncthreads();
#pragma unroll
    for (int sc = 0; sc < 8; sc++) {
      half8 wh = LDW(0, sc), uh = LDW(1, sc);
#pragma unroll
      for (int sr = 0; sr < 2; sr++) {
        racc[sr][sc] = __builtin_amdgcn_mfma_f32_16x16x32_f16(afh[sr][ks], wh, racc[sr][sc], 0, 0, 0);
        racc[sr][sc] = __builtin_amdgcn_mfma_f32_16x16x32_f16(afl[sr][ks], wh, racc[sr][sc], 0, 0, 0);
        racc[sr][sc] = __builtin_amdgcn_mfma_f32_16x16x32_f16(hfh[sr][ks], uh, racc[sr][sc], 0, 0, 0);
        racc[sr][sc] = __builtin_amdgcn_mfma_f32_16x16x32_f16(hfl[sr][ks], uh, racc[sr][sc], 0, 0, 0);
      }
    }
    __syncthreads();
    STAGE2(Wr_l, Ur_l, ks);
    asm volatile("s_waitcnt vmcnt(0)" ::: "memory");
    __syncthreads();
#pragma unroll
    for (int sc = 0; sc < 8; sc++) {
      half8 wl = LDW(0, sc), ul = LDW(1, sc);
#pragma unroll
      for (int sr = 0; sr < 2; sr++) {
        racc[sr][sc] = __builtin_amdgcn_mfma_f32_16x16x32_f16(afh[sr][ks], wl, racc[sr][sc], 0, 0, 0);
        racc[sr][sc] = __builtin_amdgcn_mfma_f32_16x16x32_f16(hfh[sr][ks], ul, racc[sr][sc], 0, 0, 0);
      }
    }
    __syncthreads();
  }
  // rh = sigmoid(pr)*h -> wave-private rows of swizzled LDS, hi AND lo
#pragma unroll
  for (int sc = 0; sc < 8; sc++) {
    const int col = sc*16 + l16;
    const float brv = bias3[128 + col];
#pragma unroll
    for (int sr = 0; sr < 2; sr++)
#pragma unroll
      for (int rg = 0; rg < 4; rg++) {
        const int lrow = w*32 + sr*16 + quad*4 + rg;     // C/D: row=quad*4+reg
        const float* hrow = h + (size_t)(row0 + lrow)*HH;
        float pr = racc[sr][sc][rg] * 0.0625f + brv;
        float rv = 1.f / (1.f + expf(-pr));
        float rhv = rv * hrow[col];
        f16 hi, lo; split1(rhv, hi, lo);
        const int off = lrow*128 + (((col>>3) ^ (lrow&7))<<3) + (col&7);
        rhh[off] = hi;
        rhl[off] = lo;
      }
  }
  asm volatile("s_waitcnt lgkmcnt(0)" ::: "memory");

  // ---- Pass 2: z = sigmoid(a Wz^T + h Uz^T + b); zacc stays fp32 ----
  floatx4 zacc[2][8];
  for (int sr = 0; sr < 2; sr++) for (int sc = 0; sc < 8; sc++) zacc[sr][sc] = zero;
#pragma unroll 1
  for (int ks = 0; ks < 4; ks++) {
    STAGE2(Wz_h, Uz_h, ks);
    asm volatile("s_waitcnt vmcnt(0)" ::: "memory");
    __syncthreads();
#pragma unroll
    for (int sc = 0; sc < 8; sc++) {
      half8 wh = LDW(0, sc), uh = LDW(1, sc);
#pragma unroll
      for (int sr = 0; sr < 2; sr++) {
        zacc[sr][sc] = __builtin_amdgcn_mfma_f32_16x16x32_f16(afh[sr][ks], wh, zacc[sr][sc], 0, 0, 0);
        zacc[sr][sc] = __builtin_amdgcn_mfma_f32_16x16x32_f16(afl[sr][ks], wh, zacc[sr][sc], 0, 0, 0);
        zacc[sr][sc] = __builtin_amdgcn_mfma_f32_16x16x32_f16(hfh[sr][ks], uh, zacc[sr][sc], 0, 0, 0);
        zacc[sr][sc] = __builtin_amdgcn_mfma_f32_16x16x32_f16(hfl[sr][ks], uh, zacc[sr][sc], 0, 0, 0);
      }
    }
    __syncthreads();
    STAGE2(Wz_l, Uz_l, ks);
    asm volatile("s_waitcnt vmcnt(0)" ::: "memory");
    __syncthreads();
#pragma unroll
    for (int sc = 0; sc < 8; sc++) {
      half8 wl = LDW(0, sc), ul = LDW(1, sc);
#pragma unroll
      for (int sr = 0; sr < 2; sr++) {
        zacc[sr][sc] = __builtin_amdgcn_mfma_f32_16x16x32_f16(afh[sr][ks], wl, zacc[sr][sc], 0, 0, 0);
        zacc[sr][sc] = __builtin_amdgcn_mfma_f32_16x16x32_f16(hfh[sr][ks], ul, zacc[sr][sc], 0, 0, 0);
      }
    }
    __syncthreads();
  }

  // ---- Pass 3: c = tanh(a Wc^T + rh Uc^T + b), all six terms ----
  floatx4 cacc[2][8];
  for (int sr = 0; sr < 2; sr++) for (int sc = 0; sc < 8; sc++) cacc[sr][sc] = zero;
#pragma unroll 1
  for (int ks = 0; ks < 4; ks++) {
    half8 rfh[2], rfl[2];
#pragma unroll
    for (int sr = 0; sr < 2; sr++) {
      const int row = w*32 + sr*16 + l16;
      const int off = row*128 + (((ks*4 + quad) ^ (l16 & 7)) << 3);
      rfh[sr] = *(const half8*)&rhh[off];
      rfl[sr] = *(const half8*)&rhl[off];
    }
    STAGE2(Wc_h, Uc_h, ks);
    asm volatile("s_waitcnt vmcnt(0)" ::: "memory");
    __syncthreads();
#pragma unroll
    for (int sc = 0; sc < 8; sc++) {
      half8 wh = LDW(0, sc), uh = LDW(1, sc);
#pragma unroll
      for (int sr = 0; sr < 2; sr++) {
        cacc[sr][sc] = __builtin_amdgcn_mfma_f32_16x16x32_f16(afh[sr][ks], wh, cacc[sr][sc], 0, 0, 0);
        cacc[sr][sc] = __builtin_amdgcn_mfma_f32_16x16x32_f16(afl[sr][ks], wh, cacc[sr][sc], 0, 0, 0);
        cacc[sr][sc] = __builtin_amdgcn_mfma_f32_16x16x32_f16(rfh[sr], uh, cacc[sr][sc], 0, 0, 0);
        cacc[sr][sc] = __builtin_amdgcn_mfma_f32_16x16x32_f16(rfl[sr], uh, cacc[sr][sc], 0, 0, 0);
      }
    }
    __syncthreads();
    STAGE2(Wc_l, Uc_l, ks);
    asm volatile("s_waitcnt vmcnt(0)" ::: "memory");
    __syncthreads();
#pragma unroll
    for (int sc = 0; sc < 8; sc++) {
      half8 wl = LDW(0, sc), ul = LDW(1, sc);
#pragma unroll
      for (int sr = 0; sr < 2; sr++) {
        cacc[sr][sc] = __builtin_amdgcn_mfma_f32_16x16x32_f16(afh[sr][ks], wl, cacc[sr][sc], 0, 0, 0);
        cacc[sr][sc] = __builtin_amdgcn_mfma_f32_16x16x32_f16(rfh[sr], ul, cacc[sr][sc], 0, 0, 0);
      }
    }
    __syncthreads();
  }
  // ---- final epilogue: h = (1-z)h + z c ----
#pragma unroll
  for (int sc = 0; sc < 8; sc++) {
    const int col = sc*16 + l16;
    const float bzv = bias3[col];
    const float bcv = bias3[256 + col];
#pragma unroll
    for (int sr = 0; sr < 2; sr++)
#pragma unroll
      for (int rg = 0; rg < 4; rg++) {
        const int lrow = w*32 + sr*16 + quad*4 + rg;
        float* hrow = h + (size_t)(row0 + lrow)*HH;
        float pz = zacc[sr][sc][rg] * 0.0625f + bzv;
        float zv = 1.f / (1.f + expf(-pz));
        float cv = tanhf(cacc[sr][sc][rg] * 0.0625f + bcv);
        float hv = hrow[col];
        hrow[col] = hv + zv*(cv - hv);
      }
  }
}

extern "C" void kernel_launch(void* const* d_in, const int* in_sizes, int n_in,
                              void* d_out, int out_size, void* d_ws, size_t ws_size,
                              hipStream_t stream) {
  const float* A      = (const float*)d_in[0];
  const float* hidden = (const float*)d_in[1];
  const float* b_ah   = (const float*)d_in[2];
  const float* w_z = (const float*)d_in[3];  const float* b_wz = (const float*)d_in[4];
  const float* u_z = (const float*)d_in[5];  const float* b_uz = (const float*)d_in[6];
  const float* w_r = (const float*)d_in[7];  const float* b_wr = (const float*)d_in[8];
  const float* u_r = (const float*)d_in[9];  const float* b_ur = (const float*)d_in[10];
  const float* w   = (const float*)d_in[11]; const float* b_w  = (const float*)d_in[12];
  const float* u   = (const float*)d_in[13]; const float* b_u  = (const float*)d_in[14];

  float* h = (float*)d_out;                       // fp32 h state == output [B,N,H]
  char* ws = (char*)d_ws;
  float* a32  = (float*)ws;                       // 33,554,432 B
  f16*   whi  = (f16*)(ws + 33554432);            // 196,608 B
  f16*   wlo  = (f16*)(ws + 33751040);            // 196,608 B
  float* bias3= (float*)(ws + 33947648);          // 1,536 B   (total ~33.9 MB)

  k_wsplit<<<384, 256, 0, stream>>>(w_z, u_z, w_r, u_r, w, u, whi, wlo);
  k_bsum<<<3, HH, 0, stream>>>(b_wz, b_uz, b_wr, b_ur, b_w, b_u, bias3);
  k_copy_h0<<<8192, 256, 0, stream>>>(hidden, h);

  for (int t = 0; t < TT; t++) {
    k_biggemm<<<dim3(4, BB), 256, 0, stream>>>(A, h, b_ah, a32);
    k_gates<<<512, 256, 0, stream>>>(a32, h, whi, wlo, bias3);
  }
}

// Round 7
// 821.528 us; speedup vs baseline: 3.4969x; 3.4969x over previous
//
#include <hip/hip_runtime.h>
#include <hip/hip_fp16.h>

#define BB 128
#define NN 512
#define HH 128
#define TT 4

typedef _Float16 f16;
typedef _Float16 half8 __attribute__((ext_vector_type(8)));
typedef float floatx4 __attribute__((ext_vector_type(4)));

// fp32 -> f16 hi/lo split: x ~= hi + lo, |lo| <= |x|*2^-11
__device__ __forceinline__ void split1(float x, f16& hi, f16& lo) {
  hi = (f16)x;
  lo = (f16)(x - (float)hi);
}

// ---------- one-time prep ----------

// six HxH fp32 weights, pre-scaled x16, split into f16 hi/lo AND PACKED into
// B-fragment order so gate-kernel weight loads are wave-contiguous 1KB reads:
// packed idx p = ks*4096 + sc*512 + (quad*16+l16)*8 + j  <->
// source element (n, k) with n = sc*16+l16, k = ks*32+quad*8+j.
__global__ void k_wpack(const float* __restrict__ wz, const float* __restrict__ uz,
                        const float* __restrict__ wr, const float* __restrict__ ur,
                        const float* __restrict__ wc, const float* __restrict__ uc,
                        f16* __restrict__ whi, f16* __restrict__ wlo) {
  int mat = blockIdx.x >> 6;
  int p = ((blockIdx.x & 63) << 8) + threadIdx.x;      // packed index
  const float* src = mat==0?wz : mat==1?uz : mat==2?wr : mat==3?ur : mat==4?wc : uc;
  const int j    = p & 7;
  const int lane = (p >> 3) & 63;
  const int l16  = lane & 15, quad = lane >> 4;
  const int sc   = (p >> 9) & 7;
  const int ks   = p >> 12;
  const int n = sc*16 + l16;
  const int k = ks*32 + quad*8 + j;
  float v = src[n*HH + k] * 16.0f;
  f16 hi, lo; split1(v, hi, lo);
  whi[mat*16384 + p] = hi;
  wlo[mat*16384 + p] = lo;
}

// summed gate biases: [0]=b_wz+b_uz, [1]=b_wr+b_ur, [2]=b_w+b_u
__global__ void k_bsum(const float* __restrict__ bwz, const float* __restrict__ buz,
                       const float* __restrict__ bwr, const float* __restrict__ bur,
                       const float* __restrict__ bw,  const float* __restrict__ bu,
                       float* __restrict__ bias3) {
  int b = blockIdx.x, j = threadIdx.x;
  bias3[b*HH + j] = b==0 ? bwz[j]+buz[j] : (b==1 ? bwr[j]+bur[j] : bw[j]+bu[j]);
}

__global__ void k_copy_h0(const float* __restrict__ hin, float* __restrict__ h) {
  int v = blockIdx.x * 256 + threadIdx.x;
  ((float4*)h)[v] = ((const float4*)hin)[v];
}

// ---------- per-step kernels ----------

// a32[b][n][j] = b_ah[j] + sum_m A[b][m][n] * h[b][m][j], fp32-accurate via
// hi/lo split f16 MFMA (3 passes). In-kernel transpose staging, XOR-swizzled.
// grid (4 n-tiles, 128 batch), 256 thr (4 waves), tile 128x128, BK=64.
__global__ __launch_bounds__(256) void k_biggemm(const float* __restrict__ A,
                                                 const float* __restrict__ h,
                                                 const float* __restrict__ b_ah,
                                                 float* __restrict__ a32) {
  __shared__ __align__(16) f16 Ah[128*64], Al[128*64], Hh[128*64], Hl[128*64];
  const int b = blockIdx.y, n0 = blockIdx.x * 128, tid = threadIdx.x;
  const int w = tid >> 6, L = tid & 63, quad = L >> 4, l16 = L & 15;
  const int rowsel = tid >> 5, colsel = tid & 31;
  const float* Ab = A + (size_t)b * NN * NN;
  const float* hb = h + (size_t)b * NN * HH;
  const floatx4 zero = {0.f, 0.f, 0.f, 0.f};
  floatx4 acc[2][8];
  for (int sr = 0; sr < 2; sr++) for (int sc = 0; sc < 8; sc++) acc[sr][sc] = zero;

  for (int mc = 0; mc < NN; mc += 64) {
    float4 va[8], vh[8];
#pragma unroll
    for (int i = 0; i < 8; i++) {
      int mm = rowsel * 8 + i;
      va[i] = *(const float4*)(Ab + (size_t)(mc + mm) * NN + n0 + colsel * 4);
      vh[i] = *(const float4*)(hb + (size_t)(mc + mm) * HH + colsel * 4);
    }
#pragma unroll
    for (int q = 0; q < 4; q++) {
      int c = colsel * 4 + q;
      half8 avh, avl, hvh, hvl;
#pragma unroll
      for (int i = 0; i < 8; i++) {
        f16 hi, lo;
        split1(((const float*)&va[i])[q], hi, lo); avh[i] = hi; avl[i] = lo;
        split1(((const float*)&vh[i])[q], hi, lo); hvh[i] = hi; hvl[i] = lo;
      }
      int blk = (rowsel ^ (c & 7)) * 8;
      *(half8*)&Ah[c*64 + blk] = avh;  *(half8*)&Al[c*64 + blk] = avl;
      *(half8*)&Hh[c*64 + blk] = hvh;  *(half8*)&Hl[c*64 + blk] = hvl;
    }
    __syncthreads();
#pragma unroll
    for (int ks = 0; ks < 2; ks++) {
      const int kb = ks * 4 + quad;
      half8 afh[2], afl[2], bfh[8], bfl[8];
      for (int sr = 0; sr < 2; sr++) {
        int c = w*32 + sr*16 + l16, o = c*64 + ((kb ^ (c & 7)) * 8);
        afh[sr] = *(const half8*)&Ah[o];
        afl[sr] = *(const half8*)&Al[o];
      }
      for (int sc = 0; sc < 8; sc++) {
        int c = sc*16 + l16, o = c*64 + ((kb ^ (c & 7)) * 8);
        bfh[sc] = *(const half8*)&Hh[o];
        bfl[sc] = *(const half8*)&Hl[o];
      }
      for (int sr = 0; sr < 2; sr++)
        for (int sc = 0; sc < 8; sc++) {
          acc[sr][sc] = __builtin_amdgcn_mfma_f32_16x16x32_f16(afh[sr], bfh[sc], acc[sr][sc], 0, 0, 0);
          acc[sr][sc] = __builtin_amdgcn_mfma_f32_16x16x32_f16(afh[sr], bfl[sc], acc[sr][sc], 0, 0, 0);
          acc[sr][sc] = __builtin_amdgcn_mfma_f32_16x16x32_f16(afl[sr], bfh[sc], acc[sr][sc], 0, 0, 0);
        }
    }
    __syncthreads();
  }
  float bah[8];
  for (int sc = 0; sc < 8; sc++) bah[sc] = b_ah[sc*16 + l16];
  float* ab = a32 + (size_t)b * NN * HH;
#pragma unroll
  for (int sr = 0; sr < 2; sr++)
    for (int rg = 0; rg < 4; rg++) {
      const int row = n0 + w*32 + sr*16 + quad*4 + rg;   // C/D: row=quad*4+reg
      for (int sc = 0; sc < 8; sc++)
        ab[(size_t)row*HH + sc*16 + l16] = acc[sr][sc][rg] + bah[sc];  // col=lane&15
    }
}

// gates, 128 rows of [B*N] per block (512 blocks), 256 thr = 4 waves, each wave
// owns 32 rows. Structure/numerics IDENTICAL to the passing round-4 kernel;
// ONLY the weight fetch changed: weights are pre-packed in B-fragment order so
// each load is wave-contiguous (lane*16B), touching 16 cache lines instead of
// 64 (stride-256B gather) -> 4x less L2 line traffic + L1 sharing across the
// CU's 8 waves (all read identical addresses).
//   P1: r gate, sc-tile=4 -> rh (hi/lo) to wave-private LDS.
//   P2: z+c merged, sc-tile=2, fused per-stripe h-update epilogue.
__global__ __launch_bounds__(256, 2) void k_gates(const float* __restrict__ a32,
                                                  float* __restrict__ h,
                                                  const f16* __restrict__ whi,
                                                  const f16* __restrict__ wlo,
                                                  const float* __restrict__ bias3) {
  __shared__ __align__(16) f16 rhh[128*136], rhl[128*136];
  const int row0 = blockIdx.x << 7, tid = threadIdx.x;
  const int w = tid >> 6, L = tid & 63, quad = L >> 4, l16 = L & 15;
  const float* ap[2]; const float* hp[2];
  for (int sr = 0; sr < 2; sr++) {
    int r = row0 + w*32 + sr*16 + l16;
    ap[sr] = a32 + (size_t)r * HH;
    hp[sr] = h + (size_t)r * HH;
  }
  // persistent fragments (A-op layout m=lane&15, k=quad*8+j): a and h, hi/lo
  half8 afh[2][4], afl[2][4], hfh[2][4], hfl[2][4];
#pragma unroll
  for (int sr = 0; sr < 2; sr++)
#pragma unroll
    for (int ks = 0; ks < 4; ks++) {
      const int ko = ks*32 + quad*8;
      float4 p = *(const float4*)(ap[sr] + ko);
      float4 q2 = *(const float4*)(ap[sr] + ko + 4);
      const float* v = (const float*)&p;
      const float* v2 = (const float*)&q2;
      for (int i = 0; i < 4; i++) { f16 hi, lo; split1(v[i],  hi, lo); afh[sr][ks][i]   = hi; afl[sr][ks][i]   = lo; }
      for (int i = 0; i < 4; i++) { f16 hi, lo; split1(v2[i], hi, lo); afh[sr][ks][i+4] = hi; afl[sr][ks][i+4] = lo; }
      float4 hpv = *(const float4*)(hp[sr] + ko);
      float4 hqv = *(const float4*)(hp[sr] + ko + 4);
      const float* hv1 = (const float*)&hpv;
      const float* hv2 = (const float*)&hqv;
      for (int i = 0; i < 4; i++) { f16 hi, lo; split1(hv1[i], hi, lo); hfh[sr][ks][i]   = hi; hfl[sr][ks][i]   = lo; }
      for (int i = 0; i < 4; i++) { f16 hi, lo; split1(hv2[i], hi, lo); hfh[sr][ks][i+4] = hi; hfl[sr][ks][i+4] = lo; }
    }
  const floatx4 zero = {0.f, 0.f, 0.f, 0.f};
  const f16* Wz_h = whi;            const f16* Wz_l = wlo;
  const f16* Uz_h = whi + 16384;    const f16* Uz_l = wlo + 16384;
  const f16* Wr_h = whi + 2*16384;  const f16* Wr_l = wlo + 2*16384;
  const f16* Ur_h = whi + 3*16384;  const f16* Ur_l = wlo + 3*16384;
  const f16* Wc_h = whi + 4*16384;  const f16* Wc_l = wlo + 4*16384;
  const f16* Uc_h = whi + 5*16384;  const f16* Uc_l = wlo + 5*16384;
  const int lane8 = (quad*16 + l16) * 8;           // lane-contiguous fragment offset

  // ---- Pass 1: r gate, sc tiles of 4 ----
#pragma unroll 1
  for (int scT = 0; scT < 2; scT++) {
    floatx4 racc[2][4];
    for (int sr = 0; sr < 2; sr++) for (int si = 0; si < 4; si++) racc[sr][si] = zero;
#pragma unroll
    for (int ks = 0; ks < 4; ks++) {
#pragma unroll
      for (int si = 0; si < 4; si++) {
        const int wo = ks*4096 + (scT*4 + si)*512 + lane8;   // packed B-fragment
        half8 wh = *(const half8*)(Wr_h + wo), wl = *(const half8*)(Wr_l + wo);
        half8 uh = *(const half8*)(Ur_h + wo), ul = *(const half8*)(Ur_l + wo);
#pragma unroll
        for (int sr = 0; sr < 2; sr++) {
          racc[sr][si] = __builtin_amdgcn_mfma_f32_16x16x32_f16(afh[sr][ks], wh, racc[sr][si], 0, 0, 0);
          racc[sr][si] = __builtin_amdgcn_mfma_f32_16x16x32_f16(afh[sr][ks], wl, racc[sr][si], 0, 0, 0);
          racc[sr][si] = __builtin_amdgcn_mfma_f32_16x16x32_f16(afl[sr][ks], wh, racc[sr][si], 0, 0, 0);
          racc[sr][si] = __builtin_amdgcn_mfma_f32_16x16x32_f16(hfh[sr][ks], uh, racc[sr][si], 0, 0, 0);
          racc[sr][si] = __builtin_amdgcn_mfma_f32_16x16x32_f16(hfh[sr][ks], ul, racc[sr][si], 0, 0, 0);
          racc[sr][si] = __builtin_amdgcn_mfma_f32_16x16x32_f16(hfl[sr][ks], uh, racc[sr][si], 0, 0, 0);
        }
      }
    }
    // per-tile epilogue: rh = sigmoid(pr)*h -> wave-private LDS (hi/lo)
#pragma unroll
    for (int si = 0; si < 4; si++) {
      const int col = (scT*4 + si)*16 + l16;
      const float brv = bias3[128 + col];
#pragma unroll
      for (int sr = 0; sr < 2; sr++)
#pragma unroll
        for (int rg = 0; rg < 4; rg++) {
          const int lrow = w*32 + sr*16 + quad*4 + rg;    // C/D: row=quad*4+reg
          const float* hrow = h + (size_t)(row0 + lrow)*HH;
          float pr = racc[sr][si][rg] * 0.0625f + brv;
          float rv = 1.f / (1.f + expf(-pr));
          float rhv = rv * hrow[col];
          f16 hi, lo; split1(rhv, hi, lo);
          rhh[lrow*136 + col] = hi;
          rhl[lrow*136 + col] = lo;
        }
    }
  }
  // rh region is wave-private: drain LDS writes, no block barrier
  asm volatile("s_waitcnt lgkmcnt(0)" ::: "memory");

  // ---- Pass 2: z + c merged, sc tiles of 2, fused h-update epilogue ----
#pragma unroll 1
  for (int scT = 0; scT < 4; scT++) {
    floatx4 zacc[2][2], cacc[2][2];
    for (int sr = 0; sr < 2; sr++)
      for (int si = 0; si < 2; si++) { zacc[sr][si] = zero; cacc[sr][si] = zero; }
#pragma unroll
    for (int ks = 0; ks < 4; ks++) {
      half8 rfh[2], rfl[2];
#pragma unroll
      for (int sr = 0; sr < 2; sr++) {
        int o = (w*32 + sr*16 + l16)*136 + ks*32 + quad*8;
        rfh[sr] = *(const half8*)&rhh[o];
        rfl[sr] = *(const half8*)&rhl[o];
      }
#pragma unroll
      for (int si = 0; si < 2; si++) {
        const int wo = ks*4096 + (scT*2 + si)*512 + lane8;   // packed B-fragment
        half8 wzh = *(const half8*)(Wz_h + wo), wzl = *(const half8*)(Wz_l + wo);
        half8 uzh = *(const half8*)(Uz_h + wo), uzl = *(const half8*)(Uz_l + wo);
        half8 wch = *(const half8*)(Wc_h + wo), wcl = *(const half8*)(Wc_l + wo);
        half8 uch = *(const half8*)(Uc_h + wo), ucl = *(const half8*)(Uc_l + wo);
#pragma unroll
        for (int sr = 0; sr < 2; sr++) {
          zacc[sr][si] = __builtin_amdgcn_mfma_f32_16x16x32_f16(afh[sr][ks], wzh, zacc[sr][si], 0, 0, 0);
          zacc[sr][si] = __builtin_amdgcn_mfma_f32_16x16x32_f16(afh[sr][ks], wzl, zacc[sr][si], 0, 0, 0);
          zacc[sr][si] = __builtin_amdgcn_mfma_f32_16x16x32_f16(afl[sr][ks], wzh, zacc[sr][si], 0, 0, 0);
          zacc[sr][si] = __builtin_amdgcn_mfma_f32_16x16x32_f16(hfh[sr][ks], uzh, zacc[sr][si], 0, 0, 0);
          zacc[sr][si] = __builtin_amdgcn_mfma_f32_16x16x32_f16(hfh[sr][ks], uzl, zacc[sr][si], 0, 0, 0);
          zacc[sr][si] = __builtin_amdgcn_mfma_f32_16x16x32_f16(hfl[sr][ks], uzh, zacc[sr][si], 0, 0, 0);
          cacc[sr][si] = __builtin_amdgcn_mfma_f32_16x16x32_f16(afh[sr][ks], wch, cacc[sr][si], 0, 0, 0);
          cacc[sr][si] = __builtin_amdgcn_mfma_f32_16x16x32_f16(afh[sr][ks], wcl, cacc[sr][si], 0, 0, 0);
          cacc[sr][si] = __builtin_amdgcn_mfma_f32_16x16x32_f16(afl[sr][ks], wch, cacc[sr][si], 0, 0, 0);
          cacc[sr][si] = __builtin_amdgcn_mfma_f32_16x16x32_f16(rfh[sr], uch, cacc[sr][si], 0, 0, 0);
          cacc[sr][si] = __builtin_amdgcn_mfma_f32_16x16x32_f16(rfh[sr], ucl, cacc[sr][si], 0, 0, 0);
          cacc[sr][si] = __builtin_amdgcn_mfma_f32_16x16x32_f16(rfl[sr], uch, cacc[sr][si], 0, 0, 0);
        }
      }
    }
    // fused final epilogue for this 32-col stripe (h written once, never re-read)
#pragma unroll
    for (int si = 0; si < 2; si++) {
      const int col = (scT*2 + si)*16 + l16;
      const float bzv = bias3[col];
      const float bcv = bias3[256 + col];
#pragma unroll
      for (int sr = 0; sr < 2; sr++)
#pragma unroll
        for (int rg = 0; rg < 4; rg++) {
          const int lrow = w*32 + sr*16 + quad*4 + rg;
          float* hrow = h + (size_t)(row0 + lrow)*HH;
          float pz = zacc[sr][si][rg] * 0.0625f + bzv;
          float zv = 1.f / (1.f + expf(-pz));
          float cv = tanhf(cacc[sr][si][rg] * 0.0625f + bcv);
          float hv = hrow[col];
          hrow[col] = hv + zv*(cv - hv);   // (1-z)h + z*c
        }
    }
  }
}

extern "C" void kernel_launch(void* const* d_in, const int* in_sizes, int n_in,
                              void* d_out, int out_size, void* d_ws, size_t ws_size,
                              hipStream_t stream) {
  const float* A      = (const float*)d_in[0];
  const float* hidden = (const float*)d_in[1];
  const float* b_ah   = (const float*)d_in[2];
  const float* w_z = (const float*)d_in[3];  const float* b_wz = (const float*)d_in[4];
  const float* u_z = (const float*)d_in[5];  const float* b_uz = (const float*)d_in[6];
  const float* w_r = (const float*)d_in[7];  const float* b_wr = (const float*)d_in[8];
  const float* u_r = (const float*)d_in[9];  const float* b_ur = (const float*)d_in[10];
  const float* w   = (const float*)d_in[11]; const float* b_w  = (const float*)d_in[12];
  const float* u   = (const float*)d_in[13]; const float* b_u  = (const float*)d_in[14];

  float* h = (float*)d_out;                       // fp32 h state == output [B,N,H]
  char* ws = (char*)d_ws;
  float* a32  = (float*)ws;                       // 33,554,432 B
  f16*   whi  = (f16*)(ws + 33554432);            // 196,608 B (packed B-frag order)
  f16*   wlo  = (f16*)(ws + 33751040);            // 196,608 B
  float* bias3= (float*)(ws + 33947648);          // 1,536 B   (total ~33.9 MB)

  k_wpack<<<384, 256, 0, stream>>>(w_z, u_z, w_r, u_r, w, u, whi, wlo);
  k_bsum<<<3, HH, 0, stream>>>(b_wz, b_uz, b_wr, b_ur, b_w, b_u, bias3);
  k_copy_h0<<<8192, 256, 0, stream>>>(hidden, h);

  for (int t = 0; t < TT; t++) {
    k_biggemm<<<dim3(4, BB), 256, 0, stream>>>(A, h, b_ah, a32);
    k_gates<<<512, 256, 0, stream>>>(a32, h, whi, wlo, bias3);
  }
}